// Round 3
// baseline (5082.483 us; speedup 1.0000x reference)
//
#include <hip/hip_runtime.h>
#include <hip/hip_bf16.h>

// BiLSTM-CRF forward decode, f32 exact-path implementation.
// Phases:
//   A: embedding gather + input projection GEMM -> xp[dir][s][g][b]
//   B: persistent LSTM scan, flag-based sync, coalesced [j][b] h-exchange
//   C: feats = concat(hf,hb) @ Wout^T + bout
//   D: Viterbi scan + backtrace -> int32 tags

#define S_LEN 256
#define BATCH 32
#define NTAG  24
#define NBLK_LSTM 128   // 2 dirs * 64 chunks (4 hidden units each)

// ---------------------------------------------------------------- Phase A
__global__ __launch_bounds__(256) void k_inproj(
    const int* __restrict__ sent, const float* __restrict__ embed,
    const float* __restrict__ WihF, const float* __restrict__ bihF, const float* __restrict__ bhhF,
    const float* __restrict__ WihB, const float* __restrict__ bihB, const float* __restrict__ bhhB,
    float* __restrict__ xp) {
  int tm = blockIdx.x;   // 0..127 : 64 (s,b)-rows each
  int tn = blockIdx.y;   // 0..15  : 64 g-cols each
  int dir = blockIdx.z;
  const float* Wih = dir ? WihB : WihF;
  const float* bih = dir ? bihB : bihF;
  const float* bhh = dir ? bhhB : bhhF;
  __shared__ float As[64 * 36];
  __shared__ float Bs[64 * 36];
  __shared__ int toks[64];
  int tid = threadIdx.x;
  if (tid < 64) {
    int r = tm * 64 + tid;
    int s = r >> 5, b = r & 31;
    toks[tid] = sent[b * S_LEN + s];
  }
  __syncthreads();
  int mt = tid & 15, nt = tid >> 4;
  float acc[4][4] = {};
  for (int k0 = 0; k0 < 256; k0 += 32) {
    for (int it = 0; it < 2; ++it) {
      int u = it * 256 + tid;
      int row = u >> 3, lf = u & 7;
      float4 av = *(const float4*)&embed[(size_t)toks[row] * 256 + k0 + lf * 4];
      *(float4*)&As[row * 36 + lf * 4] = av;
      int grow = tn * 64 + row;
      float4 wv = *(const float4*)&Wih[(size_t)grow * 256 + k0 + lf * 4];
      *(float4*)&Bs[row * 36 + lf * 4] = wv;
    }
    __syncthreads();
#pragma unroll
    for (int kc = 0; kc < 8; ++kc) {
      float4 a[4], w[4];
#pragma unroll
      for (int i = 0; i < 4; ++i) a[i] = *(const float4*)&As[(mt + 16 * i) * 36 + kc * 4];
#pragma unroll
      for (int j = 0; j < 4; ++j) w[j] = *(const float4*)&Bs[(nt + 16 * j) * 36 + kc * 4];
#pragma unroll
      for (int i = 0; i < 4; ++i)
#pragma unroll
        for (int j = 0; j < 4; ++j)
          acc[i][j] += a[i].x * w[j].x + a[i].y * w[j].y + a[i].z * w[j].z + a[i].w * w[j].w;
    }
    __syncthreads();
  }
#pragma unroll
  for (int i = 0; i < 4; ++i) {
    int r = tm * 64 + mt + 16 * i;
    int s = r >> 5, b = r & 31;
#pragma unroll
    for (int j = 0; j < 4; ++j) {
      int g = tn * 64 + nt + 16 * j;
      float v = acc[i][j] + bih[g] + bhh[g];
      xp[(((size_t)dir * 256 + s) * 1024 + g) * 32 + b] = v;
    }
  }
}

// ---------------------------------------------------------------- Phase B
// Persistent kernel. block = (dir, chunk of 4 hidden units).
// Lane role: ks = tid&7 (8-way k split), u = (tid>>3)&3 (unit), bt = tid>>5
// (batch group of 4). Each ks==0 lane owns all 4 gates of (unit u, batches
// b0..b0+3): after shfl reduction it applies the nonlinearities with cell
// state in registers and stores 4 contiguous h values -> hG stores per block
// are 4 full 128B lines (vs 128 scattered lines before: write-through drain
// was the R1/R2 bottleneck, WRITE_SIZE 607MB).
__global__ __launch_bounds__(256) void k_lstm(
    const float* __restrict__ WhhF, const float* __restrict__ WhhB,
    const float* __restrict__ xp,
    float* __restrict__ hG,    // [2 par][2 dir][256 j][32 b]
    float* __restrict__ hsH,   // [2 dir][256 s][256 j][32 b]
    unsigned int* __restrict__ flags) {  // [2 dir][64 chunk], zeroed per launch
  int bx = blockIdx.x;
  int dir = bx & 1;
  int chunk = bx >> 1;   // 0..63
  int j0 = chunk * 4;
  const float* Whh = dir ? WhhB : WhhF;
  int tid = threadIdx.x;
  int ks = tid & 7;
  int u  = (tid >> 3) & 3;
  int bt = tid >> 5;
  int b0 = bt * 4;

  __shared__ float Wg[256 * 20];   // [k][u*4+gate], stride 20 (bank spread)
  __shared__ float Hs[256 * 36];   // [k][b], stride 36

  // load Whh slice: Wg[k][u*4+g] = Whh[g*256 + j0+u][k]   (one-time)
  for (int idx = tid; idx < 4096; idx += 256) {
    int r = idx & 15, k = idx >> 4;
    int uu = r >> 2, g = r & 3;
    Wg[k * 20 + r] = Whh[(size_t)(g * 256 + j0 + uu) * 256 + k];
  }
  __syncthreads();

  float c_st[4] = {0.f, 0.f, 0.f, 0.f};
  float hvals[4] = {0.f, 0.f, 0.f, 0.f};

#pragma unroll 1
  for (int step = 0; step < 256; ++step) {
    int s = dir ? (255 - step) : step;
    int par = step & 1;

    // xp prefetch (ks==0 lanes; independent of sync -> hides under the wait)
    float4 xq[4];
    if (ks == 0) {
      const float* xps = xp + (((size_t)dir * 256 + s) * 1024) * 32;
#pragma unroll
      for (int g = 0; g < 4; ++g)
        xq[g] = *(const float4*)&xps[(g * 256 + j0 + u) * 32 + b0];
    }

    // wait: every wave polls all 64 flags of its dir independently
    {
      unsigned tgt = (unsigned)step;
      unsigned spins = 0;
      const unsigned int* fl = &flags[dir * 64 + (tid & 63)];
      while (true) {
        unsigned v = __hip_atomic_load(fl, __ATOMIC_RELAXED, __HIP_MEMORY_SCOPE_AGENT);
        if (__all(v >= tgt)) break;
        __builtin_amdgcn_s_sleep(1);
        if (++spins > (1u << 20)) break;   // safety: never hang the harness
      }
    }

    // stage h(par) -> Hs[k][b]  (linear copy, coalesced, L2-bypass loads)
    {
      const float* hp = hG + ((size_t)par * 2 + dir) * (256 * 32);
#pragma unroll
      for (int i = 0; i < 32; ++i) {
        int idx = i * 256 + tid;
        float v = __hip_atomic_load(&hp[idx], __ATOMIC_RELAXED, __HIP_MEMORY_SCOPE_AGENT);
        Hs[(idx >> 5) * 36 + (idx & 31)] = v;
      }
    }
    __syncthreads();   // B1: Hs ready

    // dot products: acc[gate][jb] over this lane's 32-k slice
    float acc[4][4] = {};
#pragma unroll
    for (int t = 0; t < 32; ++t) {
      int k = ks + 8 * t;
      float4 hv = *(const float4*)&Hs[k * 36 + b0];
      float4 wv = *(const float4*)&Wg[k * 20 + u * 4];
      acc[0][0] += wv.x * hv.x; acc[0][1] += wv.x * hv.y; acc[0][2] += wv.x * hv.z; acc[0][3] += wv.x * hv.w;
      acc[1][0] += wv.y * hv.x; acc[1][1] += wv.y * hv.y; acc[1][2] += wv.y * hv.z; acc[1][3] += wv.y * hv.w;
      acc[2][0] += wv.z * hv.x; acc[2][1] += wv.z * hv.y; acc[2][2] += wv.z * hv.z; acc[2][3] += wv.z * hv.w;
      acc[3][0] += wv.w * hv.x; acc[3][1] += wv.w * hv.y; acc[3][2] += wv.w * hv.z; acc[3][3] += wv.w * hv.w;
    }
    // reduce 8-way k split (lane bits 0..2)
#pragma unroll
    for (int g = 0; g < 4; ++g)
#pragma unroll
      for (int j = 0; j < 4; ++j) {
        float v = acc[g][j];
        v += __shfl_xor(v, 1);
        v += __shfl_xor(v, 2);
        v += __shfl_xor(v, 4);
        acc[g][j] = v;
      }

    if (ks == 0) {
      const float* xqf = (const float*)xq;
#pragma unroll
      for (int j = 0; j < 4; ++j) {
        float xi = acc[0][j] + xqf[0 * 4 + j];
        float xf = acc[1][j] + xqf[1 * 4 + j];
        float xg = acc[2][j] + xqf[2 * 4 + j];
        float xo = acc[3][j] + xqf[3 * 4 + j];
        float si = 1.f / (1.f + expf(-xi));
        float sf = 1.f / (1.f + expf(-xf));
        float so = 1.f / (1.f + expf(-xo));
        float tg = tanhf(xg);
        float c = sf * c_st[j] + si * tg;
        c_st[j] = c;
        hvals[j] = so * tanhf(c);
      }
      // coalesced h publish: 4 contiguous floats in row (j0+u)
      float* hn = hG + ((size_t)(par ^ 1) * 2 + dir) * (256 * 32);
      int row = j0 + u;
#pragma unroll
      for (int j = 0; j < 4; ++j)
        __hip_atomic_store(&hn[row * 32 + b0 + j], hvals[j],
                           __ATOMIC_RELAXED, __HIP_MEMORY_SCOPE_AGENT);
    }
    __syncthreads();   // B2: drains all waves' h stores (vmcnt(0) per wave)
    if (tid == 0)
      __hip_atomic_store(&flags[dir * 64 + chunk], (unsigned)(step + 1),
                         __ATOMIC_RELEASE, __HIP_MEMORY_SCOPE_AGENT);
    // archive for k_feats - off the critical path, plain coalesced store
    if (ks == 0) {
      float4 hv4;
      hv4.x = hvals[0]; hv4.y = hvals[1]; hv4.z = hvals[2]; hv4.w = hvals[3];
      *(float4*)&hsH[(((size_t)dir * 256 + s) * 256 + (j0 + u)) * 32 + b0] = hv4;
    }
  }
}

// ---------------------------------------------------------------- Phase C
__global__ __launch_bounds__(256) void k_feats(
    const float* __restrict__ hsH, const float* __restrict__ Wout,
    const float* __restrict__ bout, float* __restrict__ feats) {
  int s = blockIdx.x;
  int tid = threadIdx.x;
  __shared__ float Hl[32 * 260];
  __shared__ float Wl[24 * 260];
  float acc[3] = {};
  for (int dir = 0; dir < 2; ++dir) {
    __syncthreads();
    for (int u = tid; u < 8192; u += 256) {
      int j = u >> 5, b = u & 31;
      Hl[b * 260 + j] = hsH[(((size_t)dir * 256 + s) * 256 + j) * 32 + b];
    }
    for (int u = tid; u < 24 * 256; u += 256) {
      int t = u >> 8, j = u & 255;
      Wl[t * 260 + j] = Wout[t * 512 + dir * 256 + j];
    }
    __syncthreads();
    int b = tid & 31, th = tid >> 5;
    for (int jc = 0; jc < 64; ++jc) {
      float4 hv = *(const float4*)&Hl[b * 260 + jc * 4];
#pragma unroll
      for (int rep = 0; rep < 3; ++rep) {
        int t = rep * 8 + th;
        float4 wv = *(const float4*)&Wl[t * 260 + jc * 4];
        acc[rep] += hv.x * wv.x + hv.y * wv.y + hv.z * wv.z + hv.w * wv.w;
      }
    }
  }
  int b = tid & 31, th = tid >> 5;
#pragma unroll
  for (int rep = 0; rep < 3; ++rep) {
    int t = rep * 8 + th;
    feats[((size_t)s * 32 + b) * 24 + t] = acc[rep] + bout[t];
  }
}

// ---------------------------------------------------------------- Phase D
__global__ __launch_bounds__(64) void k_viterbi(
    const float* __restrict__ feats, const float* __restrict__ trans,
    const float* __restrict__ start_t, const float* __restrict__ stop_t,
    int* __restrict__ out) {
  int b = blockIdx.x;
  int j = threadIdx.x;
  bool act = j < NTAG;
  int j2 = act ? j : 0;
  __shared__ unsigned char idxL[255 * 24];
  __shared__ float sv[32];
  float tr[24];
#pragma unroll
  for (int i = 0; i < 24; ++i) tr[i] = trans[i * 24 + j2];
  float vj = feats[(size_t)b * 24 + j2] + start_t[j2];   // s=0: (0*32+b)*24
  if (!act) vj = -1e30f;
#pragma unroll 1
  for (int s = 1; s < 256; ++s) {
    float m = -1e30f;
    int arg = 0;
#pragma unroll
    for (int i = 0; i < 24; ++i) {
      float vi = __shfl(vj, i);
      float sc = vi + tr[i];
      if (sc > m) { m = sc; arg = i; }   // strict > keeps FIRST max (argmax semantics)
    }
    float fj = feats[((size_t)s * 32 + b) * 24 + j2];
    if (act) {
      idxL[(s - 1) * 24 + j] = (unsigned char)arg;
      vj = m + fj;
    }
  }
  if (act) sv[j] = vj + stop_t[j];
  __syncthreads();
  if (j == 0) {
    float m = sv[0];
    int tag = 0;
    for (int i = 1; i < 24; ++i)
      if (sv[i] > m) { m = sv[i]; tag = i; }
    out[b * 256 + 255] = tag;
    for (int s = 254; s >= 0; --s) {
      tag = idxL[s * 24 + tag];
      out[b * 256 + s] = tag;
    }
  }
}

// ---------------------------------------------------------------- host
extern "C" void kernel_launch(void* const* d_in, const int* in_sizes, int n_in,
                              void* d_out, int out_size, void* d_ws, size_t ws_size,
                              hipStream_t stream) {
  const int*   sent   = (const int*)  d_in[0];
  const float* embed  = (const float*)d_in[1];
  const float* WihF   = (const float*)d_in[2];
  const float* WhhF   = (const float*)d_in[3];
  const float* bihF   = (const float*)d_in[4];
  const float* bhhF   = (const float*)d_in[5];
  const float* WihB   = (const float*)d_in[6];
  const float* WhhB   = (const float*)d_in[7];
  const float* bihB   = (const float*)d_in[8];
  const float* bhhB   = (const float*)d_in[9];
  const float* Wout   = (const float*)d_in[10];
  const float* bout   = (const float*)d_in[11];
  const float* trans  = (const float*)d_in[12];
  const float* startt = (const float*)d_in[13];
  const float* stopt  = (const float*)d_in[14];
  int* out = (int*)d_out;

  char* ws = (char*)d_ws;
  size_t off = 0;
  float* xp = (float*)(ws + off);           off += (size_t)2 * 256 * 1024 * 32 * 4;  // 64 MB
  size_t off_sync = off;
  float* hG = (float*)(ws + off);           off += (size_t)2 * 2 * 256 * 32 * 4;     // 256 KB
  unsigned int* flags = (unsigned int*)(ws + off); off += 128 * 4;
  size_t sync_len = off - off_sync;
  float* hsH = (float*)(ws + off);          off += (size_t)2 * 256 * 256 * 32 * 4;   // 16 MB
  float* feats = (float*)(ws + off);        off += (size_t)256 * 32 * 24 * 4;        // 768 KB

  // zero h ping-pong buffers + flags (flags are consumed monotonically within
  // one kernel execution -> must be re-zeroed every launch/replay)
  hipMemsetAsync(ws + off_sync, 0, sync_len, stream);

  k_inproj<<<dim3(128, 16, 2), 256, 0, stream>>>(sent, embed, WihF, bihF, bhhF,
                                                 WihB, bihB, bhhB, xp);
  k_lstm<<<NBLK_LSTM, 256, 0, stream>>>(WhhF, WhhB, xp, hG, hsH, flags);
  k_feats<<<256, 256, 0, stream>>>(hsH, Wout, bout, feats);
  k_viterbi<<<32, 64, 0, stream>>>(feats, trans, startt, stopt, out);
}

// Round 4
// 4350.627 us; speedup vs baseline: 1.1682x; 1.1682x over previous
//
#include <hip/hip_runtime.h>
#include <hip/hip_bf16.h>

// BiLSTM-CRF forward decode, f32 exact-path implementation.
// Phases:
//   A: embedding gather + input projection GEMM -> xp[dir][s][g][b]
//   B: persistent LSTM scan, RELAXED flag sync (no wbl2/inv on critical path)
//   C: feats = concat(hf,hb) @ Wout^T + bout
//   D: Viterbi scan + backtrace -> int32 tags

#define S_LEN 256
#define BATCH 32
#define NTAG  24
#define NBLK_LSTM 128   // 2 dirs * 64 chunks (4 hidden units each)

// ---------------------------------------------------------------- Phase A
__global__ __launch_bounds__(256) void k_inproj(
    const int* __restrict__ sent, const float* __restrict__ embed,
    const float* __restrict__ WihF, const float* __restrict__ bihF, const float* __restrict__ bhhF,
    const float* __restrict__ WihB, const float* __restrict__ bihB, const float* __restrict__ bhhB,
    float* __restrict__ xp) {
  int tm = blockIdx.x;   // 0..127 : 64 (s,b)-rows each
  int tn = blockIdx.y;   // 0..15  : 64 g-cols each
  int dir = blockIdx.z;
  const float* Wih = dir ? WihB : WihF;
  const float* bih = dir ? bihB : bihF;
  const float* bhh = dir ? bhhB : bhhF;
  __shared__ float As[64 * 36];
  __shared__ float Bs[64 * 36];
  __shared__ int toks[64];
  int tid = threadIdx.x;
  if (tid < 64) {
    int r = tm * 64 + tid;
    int s = r >> 5, b = r & 31;
    toks[tid] = sent[b * S_LEN + s];
  }
  __syncthreads();
  int mt = tid & 15, nt = tid >> 4;
  float acc[4][4] = {};
  for (int k0 = 0; k0 < 256; k0 += 32) {
    for (int it = 0; it < 2; ++it) {
      int u = it * 256 + tid;
      int row = u >> 3, lf = u & 7;
      float4 av = *(const float4*)&embed[(size_t)toks[row] * 256 + k0 + lf * 4];
      *(float4*)&As[row * 36 + lf * 4] = av;
      int grow = tn * 64 + row;
      float4 wv = *(const float4*)&Wih[(size_t)grow * 256 + k0 + lf * 4];
      *(float4*)&Bs[row * 36 + lf * 4] = wv;
    }
    __syncthreads();
#pragma unroll
    for (int kc = 0; kc < 8; ++kc) {
      float4 a[4], w[4];
#pragma unroll
      for (int i = 0; i < 4; ++i) a[i] = *(const float4*)&As[(mt + 16 * i) * 36 + kc * 4];
#pragma unroll
      for (int j = 0; j < 4; ++j) w[j] = *(const float4*)&Bs[(nt + 16 * j) * 36 + kc * 4];
#pragma unroll
      for (int i = 0; i < 4; ++i)
#pragma unroll
        for (int j = 0; j < 4; ++j)
          acc[i][j] += a[i].x * w[j].x + a[i].y * w[j].y + a[i].z * w[j].z + a[i].w * w[j].w;
    }
    __syncthreads();
  }
#pragma unroll
  for (int i = 0; i < 4; ++i) {
    int r = tm * 64 + mt + 16 * i;
    int s = r >> 5, b = r & 31;
#pragma unroll
    for (int j = 0; j < 4; ++j) {
      int g = tn * 64 + nt + 16 * j;
      float v = acc[i][j] + bih[g] + bhh[g];
      xp[(((size_t)dir * 256 + s) * 1024 + g) * 32 + b] = v;
    }
  }
}

// ---------------------------------------------------------------- Phase B
// Persistent kernel. block = (dir, chunk of 4 hidden units).
// SYNC DESIGN (why no release/acquire): on gfx950, agent-scope RELEASE
// lowers to buffer_wbl2 (full L2 writeback) and ACQUIRE to buffer_inv --
// 128 blocks x 256 steps of L2 flushes was the ~17us/step floor in R1-R3.
// Instead: h-stores are agent-scope relaxed atomics (write-through to MALL,
// completion tracked by vmcnt); __syncthreads() forces s_waitcnt vmcnt(0)
// in every wave before s_barrier, so by the time tid 0 publishes the flag
// (RELAXED store, also write-through), all h values are already at the
// coherence point. Consumers poll flags and read h with agent-scope relaxed
// loads (served at MALL -> never stale). No L2 writeback/invalidate anywhere.
__global__ __launch_bounds__(256) void k_lstm(
    const float* __restrict__ WhhF, const float* __restrict__ WhhB,
    const float* __restrict__ xp,
    float* __restrict__ hG,    // [2 par][2 dir][256 j][32 b]
    float* __restrict__ hsH,   // [2 dir][256 s][256 j][32 b]
    unsigned int* __restrict__ flags) {  // [2 dir][64 chunk], zeroed per launch
  int bx = blockIdx.x;
  int dir = bx & 1;
  int chunk = bx >> 1;   // 0..63
  int j0 = chunk * 4;
  const float* Whh = dir ? WhhB : WhhF;
  int tid = threadIdx.x;
  int ks = tid & 7;
  int u  = (tid >> 3) & 3;
  int bt = tid >> 5;
  int b0 = bt * 4;

  __shared__ float Wg[256 * 20];   // [k][u*4+gate], stride 20 (bank spread)
  __shared__ float Hs[256 * 36];   // [k][b], stride 36

  // load Whh slice: Wg[k][u*4+g] = Whh[g*256 + j0+u][k]   (one-time)
  for (int idx = tid; idx < 4096; idx += 256) {
    int r = idx & 15, k = idx >> 4;
    int uu = r >> 2, g = r & 3;
    Wg[k * 20 + r] = Whh[(size_t)(g * 256 + j0 + uu) * 256 + k];
  }
  __syncthreads();

  float c_st[4] = {0.f, 0.f, 0.f, 0.f};
  float hvals[4] = {0.f, 0.f, 0.f, 0.f};

#pragma unroll 1
  for (int step = 0; step < 256; ++step) {
    int s = dir ? (255 - step) : step;
    int par = step & 1;

    // xp prefetch (ks==0 lanes; independent of sync -> hides under the wait)
    float4 xq[4];
    if (ks == 0) {
      const float* xps = xp + (((size_t)dir * 256 + s) * 1024) * 32;
#pragma unroll
      for (int g = 0; g < 4; ++g)
        xq[g] = *(const float4*)&xps[(g * 256 + j0 + u) * 32 + b0];
    }

    // wait: every wave polls all 64 flags of its dir independently (RELAXED)
    {
      unsigned tgt = (unsigned)step;
      unsigned spins = 0;
      const unsigned int* fl = &flags[dir * 64 + (tid & 63)];
      while (true) {
        unsigned v = __hip_atomic_load(fl, __ATOMIC_RELAXED, __HIP_MEMORY_SCOPE_AGENT);
        if (__all(v >= tgt)) break;
        __builtin_amdgcn_s_sleep(1);
        if (++spins > (1u << 20)) break;   // safety: never hang the harness
      }
    }

    // stage h(par) -> Hs[k][b]  (linear coalesced agent-scope loads)
    {
      const float* hp = hG + ((size_t)par * 2 + dir) * (256 * 32);
#pragma unroll
      for (int i = 0; i < 32; ++i) {
        int idx = i * 256 + tid;
        float v = __hip_atomic_load(&hp[idx], __ATOMIC_RELAXED, __HIP_MEMORY_SCOPE_AGENT);
        Hs[(idx >> 5) * 36 + (idx & 31)] = v;
      }
    }
    __syncthreads();   // B1: Hs ready

    // dot products: acc[gate][jb] over this lane's 32-k slice
    float acc[4][4] = {};
#pragma unroll
    for (int t = 0; t < 32; ++t) {
      int k = ks + 8 * t;
      float4 hv = *(const float4*)&Hs[k * 36 + b0];
      float4 wv = *(const float4*)&Wg[k * 20 + u * 4];
      acc[0][0] += wv.x * hv.x; acc[0][1] += wv.x * hv.y; acc[0][2] += wv.x * hv.z; acc[0][3] += wv.x * hv.w;
      acc[1][0] += wv.y * hv.x; acc[1][1] += wv.y * hv.y; acc[1][2] += wv.y * hv.z; acc[1][3] += wv.y * hv.w;
      acc[2][0] += wv.z * hv.x; acc[2][1] += wv.z * hv.y; acc[2][2] += wv.z * hv.z; acc[2][3] += wv.z * hv.w;
      acc[3][0] += wv.w * hv.x; acc[3][1] += wv.w * hv.y; acc[3][2] += wv.w * hv.z; acc[3][3] += wv.w * hv.w;
    }
    // reduce 8-way k split (lane bits 0..2)
#pragma unroll
    for (int g = 0; g < 4; ++g)
#pragma unroll
      for (int j = 0; j < 4; ++j) {
        float v = acc[g][j];
        v += __shfl_xor(v, 1);
        v += __shfl_xor(v, 2);
        v += __shfl_xor(v, 4);
        acc[g][j] = v;
      }

    if (ks == 0) {
      const float* xqf = (const float*)xq;
#pragma unroll
      for (int j = 0; j < 4; ++j) {
        float xi = acc[0][j] + xqf[0 * 4 + j];
        float xf = acc[1][j] + xqf[1 * 4 + j];
        float xg = acc[2][j] + xqf[2 * 4 + j];
        float xo = acc[3][j] + xqf[3 * 4 + j];
        float si = 1.f / (1.f + expf(-xi));
        float sf = 1.f / (1.f + expf(-xf));
        float so = 1.f / (1.f + expf(-xo));
        float tg = tanhf(xg);
        float c = sf * c_st[j] + si * tg;
        c_st[j] = c;
        hvals[j] = so * tanhf(c);
      }
      // coalesced h publish: 4 contiguous floats in row (j0+u), write-through
      float* hn = hG + ((size_t)(par ^ 1) * 2 + dir) * (256 * 32);
      int row = j0 + u;
#pragma unroll
      for (int j = 0; j < 4; ++j)
        __hip_atomic_store(&hn[row * 32 + b0 + j], hvals[j],
                           __ATOMIC_RELAXED, __HIP_MEMORY_SCOPE_AGENT);
    }
    __syncthreads();   // B2: every wave executes s_waitcnt vmcnt(0) before
                       // s_barrier -> ALL h stores are at the MALL
    if (tid == 0)
      __hip_atomic_store(&flags[dir * 64 + chunk], (unsigned)(step + 1),
                         __ATOMIC_RELAXED, __HIP_MEMORY_SCOPE_AGENT);
    // archive for k_feats - off the critical path, plain coalesced store
    if (ks == 0) {
      float4 hv4;
      hv4.x = hvals[0]; hv4.y = hvals[1]; hv4.z = hvals[2]; hv4.w = hvals[3];
      *(float4*)&hsH[(((size_t)dir * 256 + s) * 256 + (j0 + u)) * 32 + b0] = hv4;
    }
  }
}

// ---------------------------------------------------------------- Phase C
__global__ __launch_bounds__(256) void k_feats(
    const float* __restrict__ hsH, const float* __restrict__ Wout,
    const float* __restrict__ bout, float* __restrict__ feats) {
  int s = blockIdx.x;
  int tid = threadIdx.x;
  __shared__ float Hl[32 * 260];
  __shared__ float Wl[24 * 260];
  float acc[3] = {};
  for (int dir = 0; dir < 2; ++dir) {
    __syncthreads();
    for (int u = tid; u < 8192; u += 256) {
      int j = u >> 5, b = u & 31;
      Hl[b * 260 + j] = hsH[(((size_t)dir * 256 + s) * 256 + j) * 32 + b];
    }
    for (int u = tid; u < 24 * 256; u += 256) {
      int t = u >> 8, j = u & 255;
      Wl[t * 260 + j] = Wout[t * 512 + dir * 256 + j];
    }
    __syncthreads();
    int b = tid & 31, th = tid >> 5;
    for (int jc = 0; jc < 64; ++jc) {
      float4 hv = *(const float4*)&Hl[b * 260 + jc * 4];
#pragma unroll
      for (int rep = 0; rep < 3; ++rep) {
        int t = rep * 8 + th;
        float4 wv = *(const float4*)&Wl[t * 260 + jc * 4];
        acc[rep] += hv.x * wv.x + hv.y * wv.y + hv.z * wv.z + hv.w * wv.w;
      }
    }
  }
  int b = tid & 31, th = tid >> 5;
#pragma unroll
  for (int rep = 0; rep < 3; ++rep) {
    int t = rep * 8 + th;
    feats[((size_t)s * 32 + b) * 24 + t] = acc[rep] + bout[t];
  }
}

// ---------------------------------------------------------------- Phase D
__global__ __launch_bounds__(64) void k_viterbi(
    const float* __restrict__ feats, const float* __restrict__ trans,
    const float* __restrict__ start_t, const float* __restrict__ stop_t,
    int* __restrict__ out) {
  int b = blockIdx.x;
  int j = threadIdx.x;
  bool act = j < NTAG;
  int j2 = act ? j : 0;
  __shared__ unsigned char idxL[255 * 24];
  __shared__ float sv[32];
  float tr[24];
#pragma unroll
  for (int i = 0; i < 24; ++i) tr[i] = trans[i * 24 + j2];
  float vj = feats[(size_t)b * 24 + j2] + start_t[j2];   // s=0: (0*32+b)*24
  if (!act) vj = -1e30f;
#pragma unroll 1
  for (int s = 1; s < 256; ++s) {
    float m = -1e30f;
    int arg = 0;
#pragma unroll
    for (int i = 0; i < 24; ++i) {
      float vi = __shfl(vj, i);
      float sc = vi + tr[i];
      if (sc > m) { m = sc; arg = i; }   // strict > keeps FIRST max (argmax semantics)
    }
    float fj = feats[((size_t)s * 32 + b) * 24 + j2];
    if (act) {
      idxL[(s - 1) * 24 + j] = (unsigned char)arg;
      vj = m + fj;
    }
  }
  if (act) sv[j] = vj + stop_t[j];
  __syncthreads();
  if (j == 0) {
    float m = sv[0];
    int tag = 0;
    for (int i = 1; i < 24; ++i)
      if (sv[i] > m) { m = sv[i]; tag = i; }
    out[b * 256 + 255] = tag;
    for (int s = 254; s >= 0; --s) {
      tag = idxL[s * 24 + tag];
      out[b * 256 + s] = tag;
    }
  }
}

// ---------------------------------------------------------------- host
extern "C" void kernel_launch(void* const* d_in, const int* in_sizes, int n_in,
                              void* d_out, int out_size, void* d_ws, size_t ws_size,
                              hipStream_t stream) {
  const int*   sent   = (const int*)  d_in[0];
  const float* embed  = (const float*)d_in[1];
  const float* WihF   = (const float*)d_in[2];
  const float* WhhF   = (const float*)d_in[3];
  const float* bihF   = (const float*)d_in[4];
  const float* bhhF   = (const float*)d_in[5];
  const float* WihB   = (const float*)d_in[6];
  const float* WhhB   = (const float*)d_in[7];
  const float* bihB   = (const float*)d_in[8];
  const float* bhhB   = (const float*)d_in[9];
  const float* Wout   = (const float*)d_in[10];
  const float* bout   = (const float*)d_in[11];
  const float* trans  = (const float*)d_in[12];
  const float* startt = (const float*)d_in[13];
  const float* stopt  = (const float*)d_in[14];
  int* out = (int*)d_out;

  char* ws = (char*)d_ws;
  size_t off = 0;
  float* xp = (float*)(ws + off);           off += (size_t)2 * 256 * 1024 * 32 * 4;  // 64 MB
  size_t off_sync = off;
  float* hG = (float*)(ws + off);           off += (size_t)2 * 2 * 256 * 32 * 4;     // 256 KB
  unsigned int* flags = (unsigned int*)(ws + off); off += 128 * 4;
  size_t sync_len = off - off_sync;
  float* hsH = (float*)(ws + off);          off += (size_t)2 * 256 * 256 * 32 * 4;   // 16 MB
  float* feats = (float*)(ws + off);        off += (size_t)256 * 32 * 24 * 4;        // 768 KB

  // zero h ping-pong buffers + flags (flags are consumed monotonically within
  // one kernel execution -> must be re-zeroed every launch/replay)
  hipMemsetAsync(ws + off_sync, 0, sync_len, stream);

  k_inproj<<<dim3(128, 16, 2), 256, 0, stream>>>(sent, embed, WihF, bihF, bhhF,
                                                 WihB, bihB, bhhB, xp);
  k_lstm<<<NBLK_LSTM, 256, 0, stream>>>(WhhF, WhhB, xp, hG, hsH, flags);
  k_feats<<<256, 256, 0, stream>>>(hsH, Wout, bout, feats);
  k_viterbi<<<32, 64, 0, stream>>>(feats, trans, startt, stopt, out);
}

// Round 5
// 1280.123 us; speedup vs baseline: 3.9703x; 3.3986x over previous
//
#include <hip/hip_runtime.h>
#include <hip/hip_bf16.h>

// BiLSTM-CRF forward decode, f32 exact-path implementation.
// Phases:
//   P: one-time Whh transpose -> Wt[dir][k][j*4+gate]
//   A: embedding gather + input projection GEMM -> xq[dir][b][s][j*4+gate]
//   B: per-(dir,batch) persistent LSTM scan. 64 independent groups of 4
//      blocks; weights register-resident; 64-float h exchange per block/step.
//   C: feats = concat(hf,hb) @ Wout^T + bout
//   D: Viterbi scan + backtrace -> int32 tags

#define S_LEN 256
#define BATCH 32
#define NTAG  24

// ---------------------------------------------------------------- Phase P
// Wt[dir][k][j*4+g] = Whh_dir[g*256 + j][k]   (2 x 256 x 1024 floats)
__global__ __launch_bounds__(256) void k_prep(
    const float* __restrict__ WhhF, const float* __restrict__ WhhB,
    float* __restrict__ Wt) {
  int idx = blockIdx.x * 256 + threadIdx.x;   // 524288 total
  int dir = idx >> 18;
  int r = idx & 262143;
  int k = r >> 10;
  int jg = r & 1023;
  int j = jg >> 2, g = jg & 3;
  const float* W = dir ? WhhB : WhhF;
  Wt[idx] = W[(size_t)(g * 256 + j) * 256 + k];
}

// ---------------------------------------------------------------- Phase A
__global__ __launch_bounds__(256) void k_inproj(
    const int* __restrict__ sent, const float* __restrict__ embed,
    const float* __restrict__ WihF, const float* __restrict__ bihF, const float* __restrict__ bhhF,
    const float* __restrict__ WihB, const float* __restrict__ bihB, const float* __restrict__ bhhB,
    float* __restrict__ xq) {
  int tm = blockIdx.x;   // 0..127 : 64 (s,b)-rows each
  int tn = blockIdx.y;   // 0..15  : 64 g-cols each
  int dir = blockIdx.z;
  const float* Wih = dir ? WihB : WihF;
  const float* bih = dir ? bihB : bihF;
  const float* bhh = dir ? bhhB : bhhF;
  __shared__ float As[64 * 36];
  __shared__ float Bs[64 * 36];
  __shared__ int toks[64];
  int tid = threadIdx.x;
  if (tid < 64) {
    int r = tm * 64 + tid;
    int s = r >> 5, b = r & 31;
    toks[tid] = sent[b * S_LEN + s];
  }
  __syncthreads();
  int mt = tid & 15, nt = tid >> 4;
  float acc[4][4] = {};
  for (int k0 = 0; k0 < 256; k0 += 32) {
    for (int it = 0; it < 2; ++it) {
      int u = it * 256 + tid;
      int row = u >> 3, lf = u & 7;
      float4 av = *(const float4*)&embed[(size_t)toks[row] * 256 + k0 + lf * 4];
      *(float4*)&As[row * 36 + lf * 4] = av;
      int grow = tn * 64 + row;
      float4 wv = *(const float4*)&Wih[(size_t)grow * 256 + k0 + lf * 4];
      *(float4*)&Bs[row * 36 + lf * 4] = wv;
    }
    __syncthreads();
#pragma unroll
    for (int kc = 0; kc < 8; ++kc) {
      float4 a[4], w[4];
#pragma unroll
      for (int i = 0; i < 4; ++i) a[i] = *(const float4*)&As[(mt + 16 * i) * 36 + kc * 4];
#pragma unroll
      for (int j = 0; j < 4; ++j) w[j] = *(const float4*)&Bs[(nt + 16 * j) * 36 + kc * 4];
#pragma unroll
      for (int i = 0; i < 4; ++i)
#pragma unroll
        for (int j = 0; j < 4; ++j)
          acc[i][j] += a[i].x * w[j].x + a[i].y * w[j].y + a[i].z * w[j].z + a[i].w * w[j].w;
    }
    __syncthreads();
  }
#pragma unroll
  for (int i = 0; i < 4; ++i) {
    int r = tm * 64 + mt + 16 * i;
    int s = r >> 5, b = r & 31;
#pragma unroll
    for (int j = 0; j < 4; ++j) {
      int gg = tn * 64 + nt + 16 * j;       // gate row 0..1023
      float v = acc[i][j] + bih[gg] + bhh[gg];
      // unit-interleaved layout: [dir][b][s][j*4 + gate]
      xq[(((size_t)(dir * 32 + b)) * 256 + s) * 1024 + (gg & 255) * 4 + (gg >> 8)] = v;
    }
  }
}

// ---------------------------------------------------------------- Phase B
// 256 blocks = 64 groups (dir,b) x 4 weight-slices q. Block (dir,b,q) owns
// units [q*64, q*64+64). Weights live in VGPRs for the whole scan
// (wreg[64] float4 per thread = 256 regs; launch_bounds(256,1) -> 512 cap).
// Wave w = k-slice [w*64, w*64+64); lane l within wave owns unit q*64+l.
// Per step: poll group's 4 flags -> load 64 h values (one per lane, sc1) ->
// 64 x (shfl-broadcast h[k] + 4 FMA) -> LDS cross-wave reduce (1 barrier) ->
// wave 0 nonlinearity (c in regs) -> 64-float h publish + flag.
// Ordering: own flag gates own waves' next-step red writes (WAR safe);
// h stores are vmcnt-drained (inline s_waitcnt) before the flag store.
__global__ __launch_bounds__(256, 1) void k_lstm(
    const float* __restrict__ Wt,     // [2][256][1024]
    const float* __restrict__ xq,     // [2][32][256][1024]
    float* __restrict__ hX,           // [2 par][2 dir][32 b][256 j]
    float* __restrict__ hsF,          // [2 dir][32 b][256 s][256 j]
    unsigned int* __restrict__ flags) {  // [64 gid][32] (one line per group)
  int B = blockIdx.x;
  int q = (B >> 3) & 3;                    // weight slice
  int gid = (B & 7) | ((B >> 5) << 3);     // group id; members share XCD (mod-8 heuristic)
  int dir = gid >> 5;
  int b = gid & 31;
  int tid = threadIdx.x;
  int w = tid >> 6;        // wave = k-slice index
  int l = tid & 63;        // lane
  int kbase = w * 64;
  int unit = q * 64 + l;   // unit owned by lane l (wave 0 epilogue role)

  __shared__ float red[4][64 * 8];   // [wave][lane*8 + gate], float4-aligned

  // one-time: weight slice into registers. wreg[kk] = Wt[dir][kbase+kk][unit*4..+3]
  float4 wreg[64];
  {
    const float* wp = Wt + ((size_t)dir * 256 + kbase) * 1024 + unit * 4;
#pragma unroll
    for (int kk = 0; kk < 64; ++kk)
      wreg[kk] = *(const float4*)(wp + (size_t)kk * 1024);
  }

  float c_st = 0.f;
  const unsigned int* fl = flags + gid * 32 + (tid & 3);

#pragma unroll 1
  for (int t = 0; t < 256; ++t) {
    int s = dir ? (255 - t) : t;
    int par = t & 1;

    // wave0: prefetch xq (independent of sync -> hides under poll)
    float4 xv = {0.f, 0.f, 0.f, 0.f};
    if (w == 0)
      xv = *(const float4*)&xq[(((size_t)(dir * 32 + b)) * 256 + s) * 1024 + unit * 4];

    // poll the group's 4 flags (lane tid&3 -> flag q'), relaxed agent loads
    {
      unsigned spins = 0;
      while (true) {
        unsigned v = __hip_atomic_load(fl, __ATOMIC_RELAXED, __HIP_MEMORY_SCOPE_AGENT);
        if (__all(v >= (unsigned)t)) break;
        __builtin_amdgcn_s_sleep(1);
        if (++spins > (1u << 21)) break;   // safety: never hang the harness
      }
    }

    // stage own k-slice: lane l holds h[kbase+l] in a register
    float hval;
    {
      const float* hp = hX + (((size_t)par * 2 + dir) * 32 + b) * 256;
      hval = __hip_atomic_load(&hp[kbase + l], __ATOMIC_RELAXED, __HIP_MEMORY_SCOPE_AGENT);
    }

    // GEMV slice: acc[g] += W[unit,g][k] * h[k], h broadcast via shfl
    float4 acc = {0.f, 0.f, 0.f, 0.f};
#pragma unroll
    for (int kk = 0; kk < 64; ++kk) {
      float hk = __shfl(hval, kk);
      acc.x += wreg[kk].x * hk;
      acc.y += wreg[kk].y * hk;
      acc.z += wreg[kk].z * hk;
      acc.w += wreg[kk].w * hk;
    }
    *(float4*)&red[w][l * 8] = acc;
    __syncthreads();   // the only barrier per step

    if (w == 0) {
      float4 r0 = *(const float4*)&red[0][l * 8];
      float4 r1 = *(const float4*)&red[1][l * 8];
      float4 r2 = *(const float4*)&red[2][l * 8];
      float4 r3 = *(const float4*)&red[3][l * 8];
      float xi = r0.x + r1.x + r2.x + r3.x + xv.x;
      float xf = r0.y + r1.y + r2.y + r3.y + xv.y;
      float xg = r0.z + r1.z + r2.z + r3.z + xv.z;
      float xo = r0.w + r1.w + r2.w + r3.w + xv.w;
      float si = 1.f / (1.f + expf(-xi));
      float sf = 1.f / (1.f + expf(-xf));
      float so = 1.f / (1.f + expf(-xo));
      float tg = tanhf(xg);
      c_st = sf * c_st + si * tg;
      float h = so * tanhf(c_st);
      // publish h slice: 64 consecutive floats (2 lines), write-through
      float* hn = hX + (((size_t)(par ^ 1) * 2 + dir) * 32 + b) * 256;
      __hip_atomic_store(&hn[unit], h, __ATOMIC_RELAXED, __HIP_MEMORY_SCOPE_AGENT);
      // archive for k_feats (plain store; visible at kernel end)
      hsF[(((size_t)(dir * 32 + b)) * 256 + s) * 256 + unit] = h;
      // drain stores to the coherence point, then raise the flag
      asm volatile("s_waitcnt vmcnt(0)" ::: "memory");
      if (l == 0)
        __hip_atomic_store(&flags[gid * 32 + q], (unsigned)(t + 1),
                           __ATOMIC_RELAXED, __HIP_MEMORY_SCOPE_AGENT);
    }
    // waves 1-3 proceed to next poll; WAR on red[] is gated by own flag:
    // they cannot pass poll(t+1) until wave0 (which already read red) raises it.
  }
}

// ---------------------------------------------------------------- Phase C
__global__ __launch_bounds__(256) void k_feats(
    const float* __restrict__ hsF, const float* __restrict__ Wout,
    const float* __restrict__ bout, float* __restrict__ feats) {
  int s = blockIdx.x;
  int tid = threadIdx.x;
  __shared__ float Hl[32 * 260];
  __shared__ float Wl[24 * 260];
  float acc[3] = {};
  for (int dir = 0; dir < 2; ++dir) {
    __syncthreads();
    for (int u = tid; u < 8192; u += 256) {
      int b = u >> 8, j = u & 255;
      Hl[b * 260 + j] = hsF[(((size_t)(dir * 32 + b)) * 256 + s) * 256 + j];
    }
    for (int u = tid; u < 24 * 256; u += 256) {
      int t = u >> 8, j = u & 255;
      Wl[t * 260 + j] = Wout[t * 512 + dir * 256 + j];
    }
    __syncthreads();
    int b = tid & 31, th = tid >> 5;
    for (int jc = 0; jc < 64; ++jc) {
      float4 hv = *(const float4*)&Hl[b * 260 + jc * 4];
#pragma unroll
      for (int rep = 0; rep < 3; ++rep) {
        int t = rep * 8 + th;
        float4 wv = *(const float4*)&Wl[t * 260 + jc * 4];
        acc[rep] += hv.x * wv.x + hv.y * wv.y + hv.z * wv.z + hv.w * wv.w;
      }
    }
  }
  int b = tid & 31, th = tid >> 5;
#pragma unroll
  for (int rep = 0; rep < 3; ++rep) {
    int t = rep * 8 + th;
    feats[((size_t)s * 32 + b) * 24 + t] = acc[rep] + bout[t];
  }
}

// ---------------------------------------------------------------- Phase D
__global__ __launch_bounds__(64) void k_viterbi(
    const float* __restrict__ feats, const float* __restrict__ trans,
    const float* __restrict__ start_t, const float* __restrict__ stop_t,
    int* __restrict__ out) {
  int b = blockIdx.x;
  int j = threadIdx.x;
  bool act = j < NTAG;
  int j2 = act ? j : 0;
  __shared__ unsigned char idxL[255 * 24];
  __shared__ float sv[32];
  float tr[24];
#pragma unroll
  for (int i = 0; i < 24; ++i) tr[i] = trans[i * 24 + j2];
  float vj = feats[(size_t)b * 24 + j2] + start_t[j2];   // s=0: (0*32+b)*24
  if (!act) vj = -1e30f;
#pragma unroll 1
  for (int s = 1; s < 256; ++s) {
    float m = -1e30f;
    int arg = 0;
#pragma unroll
    for (int i = 0; i < 24; ++i) {
      float vi = __shfl(vj, i);
      float sc = vi + tr[i];
      if (sc > m) { m = sc; arg = i; }   // strict > keeps FIRST max (argmax semantics)
    }
    float fj = feats[((size_t)s * 32 + b) * 24 + j2];
    if (act) {
      idxL[(s - 1) * 24 + j] = (unsigned char)arg;
      vj = m + fj;
    }
  }
  if (act) sv[j] = vj + stop_t[j];
  __syncthreads();
  if (j == 0) {
    float m = sv[0];
    int tag = 0;
    for (int i = 1; i < 24; ++i)
      if (sv[i] > m) { m = sv[i]; tag = i; }
    out[b * 256 + 255] = tag;
    for (int s = 254; s >= 0; --s) {
      tag = idxL[s * 24 + tag];
      out[b * 256 + s] = tag;
    }
  }
}

// ---------------------------------------------------------------- host
extern "C" void kernel_launch(void* const* d_in, const int* in_sizes, int n_in,
                              void* d_out, int out_size, void* d_ws, size_t ws_size,
                              hipStream_t stream) {
  const int*   sent   = (const int*)  d_in[0];
  const float* embed  = (const float*)d_in[1];
  const float* WihF   = (const float*)d_in[2];
  const float* WhhF   = (const float*)d_in[3];
  const float* bihF   = (const float*)d_in[4];
  const float* bhhF   = (const float*)d_in[5];
  const float* WihB   = (const float*)d_in[6];
  const float* WhhB   = (const float*)d_in[7];
  const float* bihB   = (const float*)d_in[8];
  const float* bhhB   = (const float*)d_in[9];
  const float* Wout   = (const float*)d_in[10];
  const float* bout   = (const float*)d_in[11];
  const float* trans  = (const float*)d_in[12];
  const float* startt = (const float*)d_in[13];
  const float* stopt  = (const float*)d_in[14];
  int* out = (int*)d_out;

  char* ws = (char*)d_ws;
  size_t off = 0;
  float* xq = (float*)(ws + off);           off += (size_t)2 * 32 * 256 * 1024 * 4;  // 64 MB
  size_t off_sync = off;
  float* hX = (float*)(ws + off);           off += (size_t)2 * 2 * 32 * 256 * 4;     // 256 KB
  unsigned int* flags = (unsigned int*)(ws + off); off += (size_t)64 * 32 * 4;       // 8 KB
  size_t sync_len = off - off_sync;
  float* hsF = (float*)(ws + off);          off += (size_t)2 * 32 * 256 * 256 * 4;   // 16 MB
  float* feats = (float*)(ws + off);        off += (size_t)256 * 32 * 24 * 4;        // 768 KB
  float* Wt = (float*)(ws + off);           off += (size_t)2 * 256 * 1024 * 4;       // 2 MB

  // zero h ping-pong buffers + flags (consumed monotonically per execution)
  hipMemsetAsync(ws + off_sync, 0, sync_len, stream);

  k_prep<<<2048, 256, 0, stream>>>(WhhF, WhhB, Wt);
  k_inproj<<<dim3(128, 16, 2), 256, 0, stream>>>(sent, embed, WihF, bihF, bhhF,
                                                 WihB, bihB, bhhB, xq);
  k_lstm<<<256, 256, 0, stream>>>(Wt, xq, hX, hsF, flags);
  k_feats<<<256, 256, 0, stream>>>(hsF, Wout, bout, feats);
  k_viterbi<<<32, 64, 0, stream>>>(feats, trans, startt, stopt, out);
}

// Round 7
// 1127.794 us; speedup vs baseline: 4.5066x; 1.1351x over previous
//
#include <hip/hip_runtime.h>
#include <hip/hip_bf16.h>

// BiLSTM-CRF forward decode, f32 exact-path implementation.
// Phases:
//   P: one-time Whh transpose -> Wt[dir][k][j*4+gate]
//   A: embedding gather + input projection GEMM -> xq[dir][b][s][j*4+gate]
//   B: per-(dir,batch) persistent LSTM scan. 64 independent groups of 4
//      blocks; weights register-resident. Handshake: STAMPED 8-byte ATOMS
//      {h:f32, stamp:u32} - one relaxed agent load = detect + data. No
//      flags, no drains, no release/acquire (R6's sc0 experiment reverted).
//   C: feats = concat(hf,hb) @ Wout^T + bout
//   D: Viterbi scan + backtrace -> int32 tags

#define S_LEN 256
#define BATCH 32
#define NTAG  24

// ---------------------------------------------------------------- Phase P
// Wt[dir][k][j*4+g] = Whh_dir[g*256 + j][k]   (2 x 256 x 1024 floats)
__global__ __launch_bounds__(256) void k_prep(
    const float* __restrict__ WhhF, const float* __restrict__ WhhB,
    float* __restrict__ Wt) {
  int idx = blockIdx.x * 256 + threadIdx.x;   // 524288 total
  int dir = idx >> 18;
  int r = idx & 262143;
  int k = r >> 10;
  int jg = r & 1023;
  int j = jg >> 2, g = jg & 3;
  const float* W = dir ? WhhB : WhhF;
  Wt[idx] = W[(size_t)(g * 256 + j) * 256 + k];
}

// ---------------------------------------------------------------- Phase A
__global__ __launch_bounds__(256) void k_inproj(
    const int* __restrict__ sent, const float* __restrict__ embed,
    const float* __restrict__ WihF, const float* __restrict__ bihF, const float* __restrict__ bhhF,
    const float* __restrict__ WihB, const float* __restrict__ bihB, const float* __restrict__ bhhB,
    float* __restrict__ xq) {
  int tm = blockIdx.x;   // 0..127 : 64 (s,b)-rows each
  int tn = blockIdx.y;   // 0..15  : 64 g-cols each
  int dir = blockIdx.z;
  const float* Wih = dir ? WihB : WihF;
  const float* bih = dir ? bihB : bihF;
  const float* bhh = dir ? bhhB : bhhF;
  __shared__ float As[64 * 36];
  __shared__ float Bs[64 * 36];
  __shared__ int toks[64];
  int tid = threadIdx.x;
  if (tid < 64) {
    int r = tm * 64 + tid;
    int s = r >> 5, b = r & 31;
    toks[tid] = sent[b * S_LEN + s];
  }
  __syncthreads();
  int mt = tid & 15, nt = tid >> 4;
  float acc[4][4] = {};
  for (int k0 = 0; k0 < 256; k0 += 32) {
    for (int it = 0; it < 2; ++it) {
      int u = it * 256 + tid;
      int row = u >> 3, lf = u & 7;
      float4 av = *(const float4*)&embed[(size_t)toks[row] * 256 + k0 + lf * 4];
      *(float4*)&As[row * 36 + lf * 4] = av;
      int grow = tn * 64 + row;
      float4 wv = *(const float4*)&Wih[(size_t)grow * 256 + k0 + lf * 4];
      *(float4*)&Bs[row * 36 + lf * 4] = wv;
    }
    __syncthreads();
#pragma unroll
    for (int kc = 0; kc < 8; ++kc) {
      float4 a[4], w[4];
#pragma unroll
      for (int i = 0; i < 4; ++i) a[i] = *(const float4*)&As[(mt + 16 * i) * 36 + kc * 4];
#pragma unroll
      for (int j = 0; j < 4; ++j) w[j] = *(const float4*)&Bs[(nt + 16 * j) * 36 + kc * 4];
#pragma unroll
      for (int i = 0; i < 4; ++i)
#pragma unroll
        for (int j = 0; j < 4; ++j)
          acc[i][j] += a[i].x * w[j].x + a[i].y * w[j].y + a[i].z * w[j].z + a[i].w * w[j].w;
    }
    __syncthreads();
  }
#pragma unroll
  for (int i = 0; i < 4; ++i) {
    int r = tm * 64 + mt + 16 * i;
    int s = r >> 5, b = r & 31;
#pragma unroll
    for (int j = 0; j < 4; ++j) {
      int gg = tn * 64 + nt + 16 * j;       // gate row 0..1023
      float v = acc[i][j] + bih[gg] + bhh[gg];
      // unit-interleaved layout: [dir][b][s][j*4 + gate]
      xq[(((size_t)(dir * 32 + b)) * 256 + s) * 1024 + (gg & 255) * 4 + (gg >> 8)] = v;
    }
  }
}

// ---------------------------------------------------------------- Phase B
// 256 blocks = 64 groups (dir,b) x 4 weight-slices q. Block (dir,b,q) owns
// units [q*64, q*64+64); weights in VGPRs/AGPRs for the whole scan.
// Handshake: hX2[par][dir][b][unit] holds an 8-byte atom {h, stamp}.
// Producer (wave0 lane l) stores {h, t+1} into buf[(t+1)&1] - no drain, no
// flag. Consumer lane (w,l) polls atom k=w*64+l of buf[t&1] until stamp==t;
// 8B-aligned accesses are single-copy atomic, so value+stamp arrive
// consistently. Depth-2 ping-pong WAR safety is transitive: a producer
// reaches its t+2 write only after consuming all members' t+1 atoms, which
// were published only after those members consumed buf@t.
// memset-0 per launch = {h=0, stamp=0} = the t=0 initial state.
__global__ __launch_bounds__(256, 1) void k_lstm(
    const float* __restrict__ Wt,            // [2][256][1024]
    const float* __restrict__ xq,            // [2][32][256][1024]
    unsigned long long* __restrict__ hX2,    // [2 par][2 dir][32 b][256 unit]
    float* __restrict__ hsF) {               // [2 dir][32 b][256 s][256 j]
  int B = blockIdx.x;
  int q = (B >> 3) & 3;                    // weight slice
  int gid = (B & 7) | ((B >> 5) << 3);     // group id (members differ only in q)
  int dir = gid >> 5;
  int b = gid & 31;
  int tid = threadIdx.x;
  int w = tid >> 6;        // wave = k-slice index
  int l = tid & 63;        // lane
  int kbase = w * 64;
  int unit = q * 64 + l;   // unit owned by lane l (wave 0 epilogue role)

  __shared__ float red[4][64 * 8];   // [wave][lane*8 + gate], float4-aligned

  // one-time: weight slice into registers. wreg[kk] = Wt[dir][kbase+kk][unit*4..+3]
  float4 wreg[64];
  {
    const float* wp = Wt + ((size_t)dir * 256 + kbase) * 1024 + unit * 4;
#pragma unroll
    for (int kk = 0; kk < 64; ++kk)
      wreg[kk] = *(const float4*)(wp + (size_t)kk * 1024);
  }

  float c_st = 0.f;

#pragma unroll 1
  for (int t = 0; t < 256; ++t) {
    int s = dir ? (255 - t) : t;

    // wave0: prefetch xq (independent of sync -> hides under poll)
    float4 xv = {0.f, 0.f, 0.f, 0.f};
    if (w == 0)
      xv = *(const float4*)&xq[(((size_t)(dir * 32 + b)) * 256 + s) * 1024 + unit * 4];

    // poll own atom of buf[t&1] until stamp == t; payload rides along
    float hval;
    {
      const unsigned long long* hp =
          hX2 + ((((size_t)(t & 1) * 2 + dir) * 32 + b) * 256 + kbase + l);
      unsigned long long a;
      unsigned spins = 0;
      while (true) {
        a = __hip_atomic_load(hp, __ATOMIC_RELAXED, __HIP_MEMORY_SCOPE_AGENT);
        if (__all((unsigned)(a >> 32) == (unsigned)t)) break;
        if (++spins > (1u << 18)) break;   // safety: never hang the harness
      }
      hval = __uint_as_float((unsigned)a);
    }

    // GEMV slice: acc[g] += W[unit,g][k] * h[k], h broadcast via shfl
    float4 acc = {0.f, 0.f, 0.f, 0.f};
#pragma unroll
    for (int kk = 0; kk < 64; ++kk) {
      float hk = __shfl(hval, kk);
      acc.x += wreg[kk].x * hk;
      acc.y += wreg[kk].y * hk;
      acc.z += wreg[kk].z * hk;
      acc.w += wreg[kk].w * hk;
    }
    *(float4*)&red[w][l * 8] = acc;
    __syncthreads();   // the only barrier per step

    if (w == 0) {
      float4 r0 = *(const float4*)&red[0][l * 8];
      float4 r1 = *(const float4*)&red[1][l * 8];
      float4 r2 = *(const float4*)&red[2][l * 8];
      float4 r3 = *(const float4*)&red[3][l * 8];
      float xi = r0.x + r1.x + r2.x + r3.x + xv.x;
      float xf = r0.y + r1.y + r2.y + r3.y + xv.y;
      float xg = r0.z + r1.z + r2.z + r3.z + xv.z;
      float xo = r0.w + r1.w + r2.w + r3.w + xv.w;
      float si = 1.f / (1.f + expf(-xi));
      float sf = 1.f / (1.f + expf(-xf));
      float so = 1.f / (1.f + expf(-xo));
      float tg = tanhf(xg);
      c_st = sf * c_st + si * tg;
      float h = so * tanhf(c_st);
      // publish stamped atom {h, t+1} into buf[(t+1)&1] - no drain needed
      unsigned long long atom =
          ((unsigned long long)(unsigned)(t + 1) << 32) |
          (unsigned long long)__float_as_uint(h);
      unsigned long long* hn =
          hX2 + ((((size_t)((t + 1) & 1) * 2 + dir) * 32 + b) * 256 + unit);
      __hip_atomic_store(hn, atom, __ATOMIC_RELAXED, __HIP_MEMORY_SCOPE_AGENT);
      // archive for k_feats - plain store, off the critical path
      hsF[(((size_t)(dir * 32 + b)) * 256 + s) * 256 + unit] = h;
    }
    // waves 1-3 proceed to next poll; WAR on red[] is gated by the stamps:
    // they cannot pass poll(t+1) until our wave0 (which already read red)
    // publishes its t+1 atoms.
  }
}

// ---------------------------------------------------------------- Phase C
__global__ __launch_bounds__(256) void k_feats(
    const float* __restrict__ hsF, const float* __restrict__ Wout,
    const float* __restrict__ bout, float* __restrict__ feats) {
  int s = blockIdx.x;
  int tid = threadIdx.x;
  __shared__ float Hl[32 * 260];
  __shared__ float Wl[24 * 260];
  float acc[3] = {};
  for (int dir = 0; dir < 2; ++dir) {
    __syncthreads();
    for (int u = tid; u < 8192; u += 256) {
      int b = u >> 8, j = u & 255;
      Hl[b * 260 + j] = hsF[(((size_t)(dir * 32 + b)) * 256 + s) * 256 + j];
    }
    for (int u = tid; u < 24 * 256; u += 256) {
      int t = u >> 8, j = u & 255;
      Wl[t * 260 + j] = Wout[t * 512 + dir * 256 + j];
    }
    __syncthreads();
    int b = tid & 31, th = tid >> 5;
    for (int jc = 0; jc < 64; ++jc) {
      float4 hv = *(const float4*)&Hl[b * 260 + jc * 4];
#pragma unroll
      for (int rep = 0; rep < 3; ++rep) {
        int t = rep * 8 + th;
        float4 wv = *(const float4*)&Wl[t * 260 + jc * 4];
        acc[rep] += hv.x * wv.x + hv.y * wv.y + hv.z * wv.z + hv.w * wv.w;
      }
    }
  }
  int b = tid & 31, th = tid >> 5;
#pragma unroll
  for (int rep = 0; rep < 3; ++rep) {
    int t = rep * 8 + th;
    feats[((size_t)s * 32 + b) * 24 + t] = acc[rep] + bout[t];
  }
}

// ---------------------------------------------------------------- Phase D
__global__ __launch_bounds__(64) void k_viterbi(
    const float* __restrict__ feats, const float* __restrict__ trans,
    const float* __restrict__ start_t, const float* __restrict__ stop_t,
    int* __restrict__ out) {
  int b = blockIdx.x;
  int j = threadIdx.x;
  bool act = j < NTAG;
  int j2 = act ? j : 0;
  __shared__ unsigned char idxL[255 * 24];
  __shared__ float sv[32];
  float tr[24];
#pragma unroll
  for (int i = 0; i < 24; ++i) tr[i] = trans[i * 24 + j2];
  float vj = feats[(size_t)b * 24 + j2] + start_t[j2];   // s=0: (0*32+b)*24
  if (!act) vj = -1e30f;
#pragma unroll 1
  for (int s = 1; s < 256; ++s) {
    float m = -1e30f;
    int arg = 0;
#pragma unroll
    for (int i = 0; i < 24; ++i) {
      float vi = __shfl(vj, i);
      float sc = vi + tr[i];
      if (sc > m) { m = sc; arg = i; }   // strict > keeps FIRST max (argmax semantics)
    }
    float fj = feats[((size_t)s * 32 + b) * 24 + j2];
    if (act) {
      idxL[(s - 1) * 24 + j] = (unsigned char)arg;
      vj = m + fj;
    }
  }
  if (act) sv[j] = vj + stop_t[j];
  __syncthreads();
  if (j == 0) {
    float m = sv[0];
    int tag = 0;
    for (int i = 1; i < 24; ++i)
      if (sv[i] > m) { m = sv[i]; tag = i; }
    out[b * 256 + 255] = tag;
    for (int s = 254; s >= 0; --s) {
      tag = idxL[s * 24 + tag];
      out[b * 256 + s] = tag;
    }
  }
}

// ---------------------------------------------------------------- host
extern "C" void kernel_launch(void* const* d_in, const int* in_sizes, int n_in,
                              void* d_out, int out_size, void* d_ws, size_t ws_size,
                              hipStream_t stream) {
  const int*   sent   = (const int*)  d_in[0];
  const float* embed  = (const float*)d_in[1];
  const float* WihF   = (const float*)d_in[2];
  const float* WhhF   = (const float*)d_in[3];
  const float* bihF   = (const float*)d_in[4];
  const float* bhhF   = (const float*)d_in[5];
  const float* WihB   = (const float*)d_in[6];
  const float* WhhB   = (const float*)d_in[7];
  const float* bihB   = (const float*)d_in[8];
  const float* bhhB   = (const float*)d_in[9];
  const float* Wout   = (const float*)d_in[10];
  const float* bout   = (const float*)d_in[11];
  const float* trans  = (const float*)d_in[12];
  const float* startt = (const float*)d_in[13];
  const float* stopt  = (const float*)d_in[14];
  int* out = (int*)d_out;

  char* ws = (char*)d_ws;
  size_t off = 0;
  float* xq = (float*)(ws + off);           off += (size_t)2 * 32 * 256 * 1024 * 4;  // 64 MB
  size_t off_sync = off;
  unsigned long long* hX2 = (unsigned long long*)(ws + off);
                                            off += (size_t)2 * 2 * 32 * 256 * 8;     // 1 MB
  size_t sync_len = off - off_sync;
  float* hsF = (float*)(ws + off);          off += (size_t)2 * 32 * 256 * 256 * 4;   // 16 MB
  float* feats = (float*)(ws + off);        off += (size_t)256 * 32 * 24 * 4;        // 768 KB
  float* Wt = (float*)(ws + off);           off += (size_t)2 * 256 * 1024 * 4;       // 2 MB

  // zero the stamped-atom ping-pong ({h=0, stamp=0} == t=0 initial state);
  // stamps are consumed monotonically -> must re-zero every launch/replay
  hipMemsetAsync(ws + off_sync, 0, sync_len, stream);

  k_prep<<<2048, 256, 0, stream>>>(WhhF, WhhB, Wt);
  k_inproj<<<dim3(128, 16, 2), 256, 0, stream>>>(sent, embed, WihF, bihF, bhhF,
                                                 WihB, bihB, bhhB, xq);
  k_lstm<<<256, 256, 0, stream>>>(Wt, xq, hX2, hsF);
  k_feats<<<256, 256, 0, stream>>>(hsF, Wout, bout, feats);
  k_viterbi<<<32, 64, 0, stream>>>(feats, trans, startt, stopt, out);
}